// Round 1
// baseline (1373.096 us; speedup 1.0000x reference)
//
#include <hip/hip_runtime.h>
#include <hip/hip_bf16.h>
#include <stdint.h>

#define N_NODES 20000
#define DIM     768
#define NREL    8
#define NEDGE   320000
#define GK      6912   // NREL*DIM + DIM

typedef short short8 __attribute__((ext_vector_type(8)));
typedef float f32x4  __attribute__((ext_vector_type(4)));

__device__ __forceinline__ void async_load16(const void* g, void* l) {
  __builtin_amdgcn_global_load_lds((const __attribute__((address_space(1))) void*)g,
                                   (__attribute__((address_space(3))) void*)l,
                                   16, 0, 0);
}

// ---------------------------------------------------------------- CSR build
__global__ void count_deg_kernel(const int* __restrict__ dst, int* __restrict__ deg, int e_cnt) {
  int e = blockIdx.x * 256 + threadIdx.x;
  if (e < e_cnt) atomicAdd(&deg[dst[e]], 1);
}

__global__ void scan_kernel(const int* __restrict__ deg, int* __restrict__ offs,
                            int* __restrict__ cursor, int n) {
  __shared__ int buf[1024];
  __shared__ int carry_s;
  const int t = threadIdx.x;
  if (t == 0) carry_s = 0;
  __syncthreads();
  for (int base = 0; base < n; base += 1024) {
    int i = base + t;
    int v = (i < n) ? deg[i] : 0;
    buf[t] = v;
    __syncthreads();
    for (int off = 1; off < 1024; off <<= 1) {
      int add = (t >= off) ? buf[t - off] : 0;
      __syncthreads();
      buf[t] += add;
      __syncthreads();
    }
    int incl = buf[t];
    int c = carry_s;
    if (i < n) { int ex = c + incl - v; offs[i] = ex; cursor[i] = ex; }
    __syncthreads();
    if (t == 1023) carry_s = c + incl;
    __syncthreads();
  }
  if (t == 0) offs[n] = carry_s;
}

__global__ void scatter_kernel(const int* __restrict__ src, const int* __restrict__ dst,
                               const int* __restrict__ et, int* __restrict__ cursor,
                               int* __restrict__ es, int* __restrict__ er, int e_cnt) {
  int e = blockIdx.x * 256 + threadIdx.x;
  if (e < e_cnt) {
    int d = dst[e];
    int p = atomicAdd(&cursor[d], 1);
    es[p] = src[e];
    er[p] = et[e];
  }
}

// ---------------------------------------------------------------- fp32 -> bf16
__global__ void cvt_bf16_kernel(const float4* __restrict__ in, ushort4* __restrict__ out, int n4) {
  int i = blockIdx.x * 256 + threadIdx.x;
  if (i < n4) {
    float4 f = in[i];
    ushort4 r;
    r.x = __builtin_bit_cast(unsigned short, __float2bfloat16(f.x));
    r.y = __builtin_bit_cast(unsigned short, __float2bfloat16(f.y));
    r.z = __builtin_bit_cast(unsigned short, __float2bfloat16(f.z));
    r.w = __builtin_bit_cast(unsigned short, __float2bfloat16(f.w));
    out[i] = r;
  }
}

// ------------------------------------------------- weight transpose (f32 src [rows][DIM] -> bf16 dst [DIM][GK])
__global__ void transpose_w_kernel(const float* __restrict__ src, __hip_bfloat16* __restrict__ dst,
                                   int rows, int col_off) {
  __shared__ float tile[32][33];
  const int c0 = blockIdx.x * 32;   // source col (= dst row)
  const int r0 = blockIdx.y * 32;   // source row (= dst col)
  const int tx = threadIdx.x, ty = threadIdx.y;  // 32x8
  for (int i = ty; i < 32; i += 8) {
    int r = r0 + i, c = c0 + tx;
    tile[i][tx] = (r < rows) ? src[(size_t)r * DIM + c] : 0.f;
  }
  __syncthreads();
  for (int i = ty; i < 32; i += 8) {
    int c = c0 + i, r = r0 + tx;     // c = dst row (output feature o), r = dst col (k)
    if (r < rows)
      dst[(size_t)c * GK + col_off + r] = __float2bfloat16(tile[tx][i]);
  }
}

// ---------------------------------------------------------------- aggregation
// one block per dst node: LDS [8][768] fp32 accum over CSR edge list, then mean -> A (bf16),
// plus copy of the node's own feature row into the root columns [6144..6911].
__global__ __launch_bounds__(256) void aggregate_kernel(
    const __hip_bfloat16* __restrict__ feat,  // [N_NODES][DIM] bf16
    const int* __restrict__ offs, const int* __restrict__ es, const int* __restrict__ er,
    __hip_bfloat16* __restrict__ Abuf,        // [caprows][GK], chunk-local rows
    int node_base) {
  __shared__ float sums[NREL][DIM];
  __shared__ int cnt[NREL];
  const int t = threadIdx.x;
  const int n = node_base + blockIdx.x;
  for (int i = t; i < NREL * DIM; i += 256) (&sums[0][0])[i] = 0.f;
  if (t < NREL) cnt[t] = 0;
  __syncthreads();
  const int beg = offs[n], end = offs[n + 1];
  for (int e = beg; e < end; ++e) {
    const int s = es[e];
    const int r = er[e];
    if (t == 0) ++cnt[r];
    const uint32_t* row = (const uint32_t*)(feat + (size_t)s * DIM); // 384 u32 (bf16x2)
    float* srow = &sums[r][0];
    {
      uint32_t v = row[t];
      srow[2 * t]     += __builtin_bit_cast(float, v << 16);
      srow[2 * t + 1] += __builtin_bit_cast(float, v & 0xffff0000u);
    }
    if (t < 128) {
      int p = t + 256;
      uint32_t v = row[p];
      srow[2 * p]     += __builtin_bit_cast(float, v << 16);
      srow[2 * p + 1] += __builtin_bit_cast(float, v & 0xffff0000u);
    }
  }
  __syncthreads();
  __hip_bfloat16* arow = Abuf + (size_t)blockIdx.x * GK;
#pragma unroll
  for (int r = 0; r < NREL; ++r) {
    const float inv = 1.f / fmaxf((float)cnt[r], 1.f);
    for (int p = t; p < DIM; p += 256)
      arow[r * DIM + p] = __float2bfloat16(sums[r][p] * inv);
  }
  const uint32_t* xr = (const uint32_t*)(feat + (size_t)n * DIM);
  uint32_t* rootdst = (uint32_t*)(arow + NREL * DIM);
  for (int p = t; p < DIM / 2; p += 256) rootdst[p] = xr[p];
}

// ---------------------------------------------------------------- GEMM
// C[m,o] = sum_k A[m,k] * WT[o,k] (+bias), m97 structure: 128x128 tile, BK=64,
// global_load_lds width 16, XOR-swizzled [128][64] LDS tiles, 16x16x32 bf16 MFMA.
__global__ __launch_bounds__(256, 3) void gemm_kernel(
    const __hip_bfloat16* __restrict__ A,   // [>=mtiles*128][GK] chunk-local
    const __hip_bfloat16* __restrict__ BT,  // [DIM][GK]
    const float* __restrict__ bias,         // [DIM]
    __hip_bfloat16* __restrict__ outb,      // mode 0: relu -> bf16 (global rows)
    float* __restrict__ outf,               // mode 1: plain -> f32 (global rows)
    int mvalid, int node_base, int mode) {
  __shared__ __hip_bfloat16 Asm[128][64];
  __shared__ __hip_bfloat16 Bsm[128][64];
  const int t = threadIdx.x;
  const int lane = t & 63;
  const int wave = t >> 6;
  const int m0 = blockIdx.x * 128;
  const int n0 = blockIdx.y * 128;

  // staging: each wave covers rows wave*32 + ib*8 + (lane>>3); lane fetches the
  // global 16B granule ((lane&7) ^ (row&7)) so LDS granule (lane&7) is XOR-swizzled.
  const int srow = lane >> 3;
  const int sg = (lane & 7) ^ srow;
  const __hip_bfloat16* ag = A  + (size_t)(m0 + wave * 32 + srow) * GK + sg * 8;
  const __hip_bfloat16* bg = BT + (size_t)(n0 + wave * 32 + srow) * GK + sg * 8;

  f32x4 acc[4][4] = {};
  const int wm = (wave >> 1) * 64;
  const int wn = (wave & 1) * 64;
  const int ml = lane & 15;
  const int quad = lane >> 4;
  const int sw = ml & 7;

  for (int kt = 0; kt < GK / 64; ++kt) {
    __syncthreads();
#pragma unroll
    for (int ib = 0; ib < 4; ++ib)
      async_load16(ag + (size_t)ib * 8 * GK, &Asm[wave * 32 + ib * 8][0]);
#pragma unroll
    for (int ib = 0; ib < 4; ++ib)
      async_load16(bg + (size_t)ib * 8 * GK, &Bsm[wave * 32 + ib * 8][0]);
    ag += 64; bg += 64;
    __syncthreads();
#pragma unroll
    for (int ks = 0; ks < 2; ++ks) {
      const int go = (((ks * 4 + quad) ^ sw) * 8);
      short8 a[4], b[4];
#pragma unroll
      for (int i = 0; i < 4; ++i)
        a[i] = *(const short8*)&Asm[wm + i * 16 + ml][go];
#pragma unroll
      for (int i = 0; i < 4; ++i)
        b[i] = *(const short8*)&Bsm[wn + i * 16 + ml][go];
#pragma unroll
      for (int i = 0; i < 4; ++i)
#pragma unroll
        for (int j = 0; j < 4; ++j)
          acc[i][j] = __builtin_amdgcn_mfma_f32_16x16x32_bf16(a[i], b[j], acc[i][j], 0, 0, 0);
    }
  }

  float bcol[4];
#pragma unroll
  for (int nt = 0; nt < 4; ++nt) bcol[nt] = bias[n0 + wn + nt * 16 + ml];
#pragma unroll
  for (int mt = 0; mt < 4; ++mt) {
#pragma unroll
    for (int rr = 0; rr < 4; ++rr) {
      int row = m0 + wm + mt * 16 + quad * 4 + rr;
      if (row < mvalid) {
        size_t orow = (size_t)(node_base + row) * DIM;
#pragma unroll
        for (int nt = 0; nt < 4; ++nt) {
          int col = n0 + wn + nt * 16 + ml;
          float v = acc[mt][nt][rr] + bcol[nt];
          if (mode == 0) outb[orow + col] = __float2bfloat16(fmaxf(v, 0.f));
          else           outf[orow + col] = v;
        }
      }
    }
  }
}

// ---------------------------------------------------------------- launch
extern "C" void kernel_launch(void* const* d_in, const int* in_sizes, int n_in,
                              void* d_out, int out_size, void* d_ws, size_t ws_size,
                              hipStream_t stream) {
  const float* x     = (const float*)d_in[0];
  const int*   eidx  = (const int*)d_in[1];     // [2][E]
  const int*   etype = (const int*)d_in[2];
  const float* W1    = (const float*)d_in[3];
  const float* root1 = (const float*)d_in[4];
  const float* b1    = (const float*)d_in[5];
  const float* W2    = (const float*)d_in[6];
  const float* root2 = (const float*)d_in[7];
  const float* b2    = (const float*)d_in[8];
  float* out = (float*)d_out;
  const int* esrc_in = eidx;
  const int* edst_in = eidx + NEDGE;

  char* p = (char*)d_ws;
  auto alloc = [&](size_t bytes) -> char* {
    char* r = p;
    p += (bytes + 255) & ~(size_t)255;
    return r;
  };
  __hip_bfloat16* xb  = (__hip_bfloat16*)alloc((size_t)N_NODES * DIM * 2);
  __hip_bfloat16* hb  = (__hip_bfloat16*)alloc((size_t)N_NODES * DIM * 2);
  __hip_bfloat16* w1t = (__hip_bfloat16*)alloc((size_t)DIM * GK * 2);
  __hip_bfloat16* w2t = (__hip_bfloat16*)alloc((size_t)DIM * GK * 2);
  int* deg    = (int*)alloc((size_t)N_NODES * 4);
  int* offs   = (int*)alloc((size_t)(N_NODES + 1) * 4);
  int* cursor = (int*)alloc((size_t)N_NODES * 4);
  int* es     = (int*)alloc((size_t)NEDGE * 4);
  int* er     = (int*)alloc((size_t)NEDGE * 4);
  size_t used = (size_t)(p - (char*)d_ws);
  size_t remain = (ws_size > used) ? (ws_size - used) : 0;
  long long caprows_ll = (long long)(remain / ((size_t)GK * 2));
  int caprows = (int)((caprows_ll / 128) * 128);
  if (caprows > 20096) caprows = 20096;   // 157*128
  if (caprows < 128) caprows = 128;       // nothing sane we can do below this
  __hip_bfloat16* Abuf = (__hip_bfloat16*)p;

  // --- CSR build ---
  hipMemsetAsync(deg, 0, (size_t)N_NODES * 4, stream);
  count_deg_kernel<<<(NEDGE + 255) / 256, 256, 0, stream>>>(edst_in, deg, NEDGE);
  scan_kernel<<<1, 1024, 0, stream>>>(deg, offs, cursor, N_NODES);
  scatter_kernel<<<(NEDGE + 255) / 256, 256, 0, stream>>>(esrc_in, edst_in, etype, cursor, es, er, NEDGE);

  // --- convert x, build transposed bf16 weights ---
  cvt_bf16_kernel<<<((N_NODES * DIM / 4) + 255) / 256, 256, 0, stream>>>(
      (const float4*)x, (ushort4*)xb, N_NODES * DIM / 4);
  dim3 tb(32, 8);
  transpose_w_kernel<<<dim3(DIM / 32, (NREL * DIM) / 32), tb, 0, stream>>>(W1, w1t, NREL * DIM, 0);
  transpose_w_kernel<<<dim3(DIM / 32, DIM / 32), tb, 0, stream>>>(root1, w1t, DIM, NREL * DIM);
  transpose_w_kernel<<<dim3(DIM / 32, (NREL * DIM) / 32), tb, 0, stream>>>(W2, w2t, NREL * DIM, 0);
  transpose_w_kernel<<<dim3(DIM / 32, DIM / 32), tb, 0, stream>>>(root2, w2t, DIM, NREL * DIM);

  // --- layer 1: A = [mean_r(x) | x], h = relu(A @ W1cat + b1) -> bf16 ---
  for (int base = 0; base < N_NODES; base += caprows) {
    int rows = N_NODES - base; if (rows > caprows) rows = caprows;
    aggregate_kernel<<<rows, 256, 0, stream>>>(xb, offs, es, er, Abuf, base);
    dim3 grid((rows + 127) / 128, DIM / 128);
    gemm_kernel<<<grid, 256, 0, stream>>>(Abuf, w1t, b1, hb, nullptr, rows, base, 0);
  }
  // --- layer 2: A = [mean_r(h) | h], out = A @ W2cat + b2 -> f32 ---
  for (int base = 0; base < N_NODES; base += caprows) {
    int rows = N_NODES - base; if (rows > caprows) rows = caprows;
    aggregate_kernel<<<rows, 256, 0, stream>>>(hb, offs, es, er, Abuf, base);
    dim3 grid((rows + 127) / 128, DIM / 128);
    gemm_kernel<<<grid, 256, 0, stream>>>(Abuf, w2t, b2, nullptr, out, rows, base, 1);
  }
}